// Round 9
// baseline (395.454 us; speedup 1.0000x reference)
//
#include <hip/hip_runtime.h>
#include <hip/hip_bf16.h>
#include <cstdint>

#define DI __device__ __forceinline__

typedef unsigned short u16;
typedef __bf16 bf16x8 __attribute__((ext_vector_type(8)));
typedef float f32x4 __attribute__((ext_vector_type(4)));

constexpr int Bc  = 2;
constexpr int Sc  = 1024;
constexpr int Cc  = 1024;
constexpr int Hc  = 16;
constexpr int HDc = 64;
constexpr int S2c = 2048;
constexpr int ECc = 4096;
constexpr int BSc  = Bc * Sc;   // 2048
constexpr int BS2c = Bc * S2c;  // 4096

constexpr int EPI_KV = 0, EPI_Q = 1, EPI_O = 3, EPI_GELU = 4, EPI_FINAL = 5, EPI_PART = 6;

DI u16 f2b(float f) {
  __hip_bfloat16 h = __float2bfloat16(f);
  u16 u;
  __builtin_memcpy(&u, &h, 2);
  return u;
}

// fast bf16 pack (round-half-up); fine for p in [0,1]
DI u16 f2b_fast(float f) {
  uint32_t u;
  __builtin_memcpy(&u, &f, 4);
  return (u16)((u + 0x8000u) >> 16);
}

// CK-style direct global->LDS (16B per lane; LDS dest = wave-uniform base + lane*16)
DI void glds16(const void* g, void* l) {
  auto* lp = reinterpret_cast<__attribute__((address_space(3))) uint32_t*>(
      reinterpret_cast<uintptr_t>(l));
  __builtin_amdgcn_global_load_lds(
      reinterpret_cast<const __attribute__((address_space(1))) uint32_t*>(
          reinterpret_cast<uintptr_t>(g)),
      lp, 16, 0, 0);
}

DI f32x4 mfma16(bf16x8 a, bf16x8 b, f32x4 c) {
  return __builtin_amdgcn_mfma_f32_16x16x32_bf16(a, b, c, 0, 0, 0);
}

// ------------- fused transpose of the four CxC weights: WT[n][k] = W[k][n] -------------
__global__ __launch_bounds__(256) void transpose4_kernel(const float* __restrict__ Wq,
                                                         const float* __restrict__ Wk,
                                                         const float* __restrict__ Wv,
                                                         const float* __restrict__ Wo,
                                                         u16* __restrict__ WqT,
                                                         u16* __restrict__ WkvT,
                                                         u16* __restrict__ WoT) {
  __shared__ float tile[32][33];
  const int z = blockIdx.z;
  const float* W = (z == 0) ? Wq : (z == 1) ? Wk : (z == 2) ? Wv : Wo;
  u16* WT = (z == 0) ? WqT : (z == 1) ? WkvT : (z == 2) ? (WkvT + (size_t)Cc * Cc) : WoT;
  const int bx = blockIdx.x, by = blockIdx.y;
  const int tx = threadIdx.x, ty = threadIdx.y;
  const int c = bx * 32 + tx;
#pragma unroll
  for (int i = ty; i < 32; i += 8) tile[i][tx] = W[(size_t)(by * 32 + i) * Cc + c];
  __syncthreads();
#pragma unroll
  for (int i = ty; i < 32; i += 8)
    WT[(size_t)(bx * 32 + i) * Cc + by * 32 + tx] = f2b(tile[tx][i]);
}

// ---------------- transpose + fp32->bf16 convert: WT[n][k] = W[k][n] ----------------
__global__ __launch_bounds__(256) void transpose_kernel(const float* __restrict__ W,
                                                        u16* __restrict__ WT, int R, int Cn) {
  __shared__ float tile[32][33];
  const int bx = blockIdx.x, by = blockIdx.y;
  const int tx = threadIdx.x, ty = threadIdx.y;
  const int c = bx * 32 + tx;
#pragma unroll
  for (int i = ty; i < 32; i += 8) tile[i][tx] = W[(size_t)(by * 32 + i) * Cn + c];
  __syncthreads();
#pragma unroll
  for (int i = ty; i < 32; i += 8)
    WT[(size_t)(bx * 32 + i) * R + by * 32 + tx] = f2b(tile[tx][i]);
}

// ---------------- prep: comb + LN(comb)->cx ; LN(all_embed)->ae ----------------
__global__ __launch_bounds__(256) void prep_ln_kernel(
    const float* __restrict__ fwd, const float* __restrict__ bwd, const float* __restrict__ g,
    const float* __restrict__ be, float* __restrict__ comb, u16* __restrict__ cx,
    u16* __restrict__ ae) {
  __shared__ float red[2][4];
  const int row = blockIdx.x, tid = threadIdx.x;
  const int c = tid * 4;
  float4 x;
  u16* dst;
  if (row < BSc) {
    const int b = row >> 10, s = row & (Sc - 1);
    const float4 f = *(const float4*)(fwd + ((size_t)(b * (Sc + 1) + s)) * Cc + c);
    const float4 r = *(const float4*)(bwd + ((size_t)(b * (Sc + 1) + s + 1)) * Cc + c);
    const float k = 0.70710678118654752f;
    x.x = (f.x + r.x) * k; x.y = (f.y + r.y) * k;
    x.z = (f.z + r.z) * k; x.w = (f.w + r.w) * k;
    *(float4*)(comb + (size_t)row * Cc + c) = x;
    dst = cx + (size_t)row * Cc;
  } else {
    const int idx = row - BSc;
    const int b = idx >> 11, t = idx & (S2c - 1);
    const float* src = (t < Sc) ? (fwd + ((size_t)(b * (Sc + 1) + t)) * Cc)
                                : (bwd + ((size_t)(b * (Sc + 1) + (t - Sc) + 1)) * Cc);
    x = *(const float4*)(src + c);
    dst = ae + (size_t)idx * Cc;
  }
  float s1 = x.x + x.y + x.z + x.w;
  float s2 = x.x * x.x + x.y * x.y + x.z * x.z + x.w * x.w;
  for (int off = 32; off; off >>= 1) { s1 += __shfl_down(s1, off); s2 += __shfl_down(s2, off); }
  if ((tid & 63) == 0) { red[0][tid >> 6] = s1; red[1][tid >> 6] = s2; }
  __syncthreads();
  s1 = red[0][0] + red[0][1] + red[0][2] + red[0][3];
  s2 = red[1][0] + red[1][1] + red[1][2] + red[1][3];
  const float mean = s1 * (1.0f / Cc);
  const float rstd = rsqrtf(s2 * (1.0f / Cc) - mean * mean + 1e-5f);
  const float4 gv = *(const float4*)(g + c);
  const float4 bv = *(const float4*)(be + c);
  ushort4 o;
  o.x = f2b((x.x - mean) * rstd * gv.x + bv.x);
  o.y = f2b((x.y - mean) * rstd * gv.y + bv.y);
  o.z = f2b((x.z - mean) * rstd * gv.z + bv.z);
  o.w = f2b((x.w - mean) * rstd * gv.w + bv.w);
  *(ushort4*)(dst + c) = o;
}

// ---------------- double LN: h = LN(LN(x,g2,b2),gm,bm) ----------------
__global__ __launch_bounds__(256) void ln2_kernel(const float* __restrict__ x,
                                                  const float* __restrict__ g2,
                                                  const float* __restrict__ b2,
                                                  const float* __restrict__ gm,
                                                  const float* __restrict__ bm,
                                                  u16* __restrict__ h) {
  __shared__ float red[2][4];
  const int row = blockIdx.x, tid = threadIdx.x;
  const int c = tid * 4;
  const float4 v = *(const float4*)(x + (size_t)row * Cc + c);
  float s1 = v.x + v.y + v.z + v.w;
  float s2 = v.x * v.x + v.y * v.y + v.z * v.z + v.w * v.w;
  for (int off = 32; off; off >>= 1) { s1 += __shfl_down(s1, off); s2 += __shfl_down(s2, off); }
  if ((tid & 63) == 0) { red[0][tid >> 6] = s1; red[1][tid >> 6] = s2; }
  __syncthreads();
  s1 = red[0][0] + red[0][1] + red[0][2] + red[0][3];
  s2 = red[1][0] + red[1][1] + red[1][2] + red[1][3];
  float mean = s1 * (1.0f / Cc);
  float rstd = rsqrtf(s2 * (1.0f / Cc) - mean * mean + 1e-5f);
  const float4 ga = *(const float4*)(g2 + c);
  const float4 ba = *(const float4*)(b2 + c);
  const float t0 = (v.x - mean) * rstd * ga.x + ba.x;
  const float t1 = (v.y - mean) * rstd * ga.y + ba.y;
  const float t2 = (v.z - mean) * rstd * ga.z + ba.z;
  const float t3 = (v.w - mean) * rstd * ga.w + ba.w;
  s1 = t0 + t1 + t2 + t3;
  s2 = t0 * t0 + t1 * t1 + t2 * t2 + t3 * t3;
  for (int off = 32; off; off >>= 1) { s1 += __shfl_down(s1, off); s2 += __shfl_down(s2, off); }
  __syncthreads();
  if ((tid & 63) == 0) { red[0][tid >> 6] = s1; red[1][tid >> 6] = s2; }
  __syncthreads();
  s1 = red[0][0] + red[0][1] + red[0][2] + red[0][3];
  s2 = red[1][0] + red[1][1] + red[1][2] + red[1][3];
  mean = s1 * (1.0f / Cc);
  rstd = rsqrtf(s2 * (1.0f / Cc) - mean * mean + 1e-5f);
  const float4 gb = *(const float4*)(gm + c);
  const float4 bb = *(const float4*)(bm + c);
  ushort4 o;
  o.x = f2b((t0 - mean) * rstd * gb.x + bb.x);
  o.y = f2b((t1 - mean) * rstd * gb.y + bb.y);
  o.z = f2b((t2 - mean) * rstd * gb.z + bb.z);
  o.w = f2b((t3 - mean) * rstd * gb.w + bb.w);
  *(ushort4*)(h + (size_t)row * Cc + c) = o;
}

// ---------------- GEMM: Y = A(MxK) @ BT(NxK)^T, fused epilogues ----------------
// 128x128 tile, 4 waves (64x64 each), BK=32, glds16 staging, 2-barrier K-loop
// (the R5-benched structure — best measured). Optional split-K via gridDim.z:
// slice z covers K/SK; EPI_PART writes raw f32 partials to pbuf[z].
template <int EPI, int SK>
__global__ __launch_bounds__(256) void gemm_kernel(
    const u16* __restrict__ A, const u16* __restrict__ BT, const float* __restrict__ bias,
    const float* __restrict__ bias2, const float* __restrict__ pos,
    u16* __restrict__ outb, u16* __restrict__ out2, float* __restrict__ pbuf,
    int M, int N, int K) {
  __shared__ u16 Asm[128 * 32];
  __shared__ u16 Bsm[128 * 32];
  const int tid = threadIdx.x;
  const int w = tid >> 6, lane = tid & 63, quad = lane >> 4, r16 = lane & 15;
  const int bm = blockIdx.y * 128, bn = blockIdx.x * 128;
  const int wm = (w & 1) * 64, wn = (w >> 1) * 64;
  const int Ks = K / SK, kb0 = blockIdx.z * Ks;

  const int srow = lane >> 2, scol = (lane & 3) * 8;
  const u16* aP = A + (size_t)(bm + w * 32 + srow) * K + kb0 + scol;
  const u16* bP = BT + (size_t)(bn + w * 32 + srow) * K + kb0 + scol;
  u16* aL0 = &Asm[(w * 32) * 32];
  u16* aL1 = &Asm[(w * 32 + 16) * 32];
  u16* bL0 = &Bsm[(w * 32) * 32];
  u16* bL1 = &Bsm[(w * 32 + 16) * 32];
  const size_t rstep = (size_t)16 * K;

  f32x4 acc[4][4] = {};

  for (int k0 = 0; k0 < Ks; k0 += 32) {
    glds16(aP, aL0);
    glds16(aP + rstep, aL1);
    glds16(bP, bL0);
    glds16(bP + rstep, bL1);
    aP += 32;
    bP += 32;
    __syncthreads();
    bf16x8 af[4], bfr[4];
#pragma unroll
    for (int i = 0; i < 4; i++) {
      af[i] = *reinterpret_cast<const bf16x8*>(&Asm[(wm + i * 16 + r16) * 32 + quad * 8]);
      bfr[i] = *reinterpret_cast<const bf16x8*>(&Bsm[(wn + i * 16 + r16) * 32 + quad * 8]);
    }
#pragma unroll
    for (int mi = 0; mi < 4; mi++)
#pragma unroll
      for (int ni = 0; ni < 4; ni++) acc[mi][ni] = mfma16(af[mi], bfr[ni], acc[mi][ni]);
    __syncthreads();
  }

#pragma unroll
  for (int mi = 0; mi < 4; mi++) {
#pragma unroll
    for (int ni = 0; ni < 4; ni++) {
      const int col = bn + wn + ni * 16 + r16;
      const int row0 = bm + wm + mi * 16 + quad * 4;
      if constexpr (EPI == EPI_PART) {
        float* pb = pbuf + (size_t)blockIdx.z * M * N;
#pragma unroll
        for (int r = 0; r < 4; r++) pb[(size_t)(row0 + r) * N + col] = acc[mi][ni][r];
      } else if constexpr (EPI == EPI_KV) {
        if (col < Cc) {
#pragma unroll
          for (int r = 0; r < 4; r++) {
            const int row = row0 + r;
            const int key = row & (S2c - 1);
            const float y =
                acc[mi][ni][r] + bias[col] + pos[(key & (Sc - 1)) * HDc + (col & 63)];
            outb[(size_t)row * Cc + col] = f2b(y);
          }
        } else {
          const int c2 = col - Cc;
          const int h = c2 >> 6, d = c2 & 63;
          const int b = row0 >> 11, key0 = row0 & (S2c - 1);
          const float bb = bias2[c2];
          ushort4 pk;
          pk.x = f2b(acc[mi][ni][0] + bb);
          pk.y = f2b(acc[mi][ni][1] + bb);
          pk.z = f2b(acc[mi][ni][2] + bb);
          pk.w = f2b(acc[mi][ni][3] + bb);
          *(ushort4*)&out2[(((size_t)(b * Hc + h) * HDc + d) << 11) + key0] = pk;
        }
      } else {  // EPI_GELU
#pragma unroll
        for (int r = 0; r < 4; r++) {
          const float y = acc[mi][ni][r] + bias[col];
          outb[(size_t)(row0 + r) * N + col] =
              f2b(0.5f * y * (1.0f + erff(y * 0.70710678118654752f)));
        }
      }
    }
  }
}

// ---------------- split-K reduce + epilogue (SK slices of MxN f32) ----------------
// EPI_Q: out = bf16((sum + bias + pos) * scale) ; EPI_O/EPI_FINAL: out = f32(sum + bias + add)
template <int EPI, int SK>
__global__ __launch_bounds__(256) void reduce_kernel(const float* __restrict__ pbuf,
                                                     const float* __restrict__ bias,
                                                     const float* __restrict__ pos,
                                                     const float* __restrict__ addsrc,
                                                     u16* __restrict__ outb,
                                                     float* __restrict__ outf, int M, int N) {
  const size_t flat = ((size_t)blockIdx.x * 256 + threadIdx.x) * 4;
  const int row = (int)(flat / N), col = (int)(flat % N);
  const size_t MN = (size_t)M * N;
  float4 s = *(const float4*)(pbuf + flat);
#pragma unroll
  for (int z = 1; z < SK; z++) {
    const float4 v = *(const float4*)(pbuf + z * MN + flat);
    s.x += v.x; s.y += v.y; s.z += v.z; s.w += v.w;
  }
  const float4 bv = *(const float4*)(bias + col);
  s.x += bv.x; s.y += bv.y; s.z += bv.z; s.w += bv.w;
  if constexpr (EPI == EPI_Q) {
    const int sq = row & (Sc - 1), d = col & 63;
    const float4 pv = *(const float4*)(pos + sq * HDc + d);
    constexpr float sc = 0.180336880111120426f;  // (1/8)*log2(e)
    ushort4 o;
    o.x = f2b((s.x + pv.x) * sc);
    o.y = f2b((s.y + pv.y) * sc);
    o.z = f2b((s.z + pv.z) * sc);
    o.w = f2b((s.w + pv.w) * sc);
    *(ushort4*)(outb + flat) = o;
  } else {
    const float4 av = *(const float4*)(addsrc + flat);
    float4 o;
    o.x = s.x + av.x; o.y = s.y + av.y; o.z = s.z + av.z; o.w = s.w + av.w;
    *(float4*)(outf + flat) = o;
  }
}

// ---------------- attention partials: grid (bh, qt, half); 4 indep waves x 16 queries ------
// Software-pipelined: V loads issue first (older in vmcnt order), then next unit's K
// prefetch (ping-pong regs), then QK on the PREVIOUS prefetch (no wait). PV's wait on V
// leaves the K-prefetch in flight. launch_bounds(256,3): room for ~150 live VGPRs so the
// compiler keeps all 16 staging fragments in parallel (R8's 56-VGPR allocation serialized
// the loads -> 5000cy/unit exposed latency).
__global__ __launch_bounds__(256, 3) void attn_part_kernel(const u16* __restrict__ qb,
                                                           const u16* __restrict__ kb,
                                                           const u16* __restrict__ vT,
                                                           float* __restrict__ o_part,
                                                           float* __restrict__ l_part) {
  const int bh = blockIdx.x;
  const int qt = blockIdx.y;
  const int half = blockIdx.z;
  const int b = bh >> 4, head = bh & 15;
  const int tid = threadIdx.x;
  const int w = tid >> 6, lane = tid & 63, quad = lane >> 4, r16 = lane & 15;

  __shared__ u16 Ps[4][16 * 68];  // per-wave P round-trip (stride 68: conflict-free)
  u16* ps = Ps[w];

  const int q0 = qt * 64;
  const int qw = q0 + w * 16;  // this wave's 16 queries

  bf16x8 aq[2];
  {
    const u16* qp = qb + ((size_t)((b * Sc + qw + r16) * Hc + head)) * HDc + quad * 8;
    aq[0] = *(const bf16x8*)qp;
    aq[1] = *(const bf16x8*)(qp + 32);
  }

  const size_t krow = (size_t)Hc * HDc;
  const u16* kbase = kb + ((size_t)b * S2c * Hc + head) * HDc;
  const u16* vbase = vT + ((size_t)(b * Hc + head)) * HDc * S2c;

  f32x4 o_acc[4] = {};
  float lsum[4] = {};

  const int n = (half == 0) ? (qt + 1) : (16 - qt);
  const int kb0 = (half == 0) ? 0 : Sc + qt * 64;  // unit j covers keys kb0 + j*64 ..

  bf16x8 KA[2][4], KB[2][4];

  auto loadK = [&](int j, bf16x8 (&D)[2][4]) {
    const int k0 = kb0 + j * 64;
#pragma unroll
    for (int ks = 0; ks < 2; ks++)
#pragma unroll
      for (int ni = 0; ni < 4; ni++)
        D[ks][ni] = *(const bf16x8*)(kbase + (size_t)(k0 + ni * 16 + r16) * krow +
                                     ks * 32 + quad * 8);
  };

  auto unit = [&](int j, bf16x8 (&K)[2][4], bf16x8 (&Kn)[2][4]) {
    const int k0 = kb0 + j * 64;
    // V loads first: older than the K-prefetch in vmcnt order
    bf16x8 V[2][4];
#pragma unroll
    for (int ks = 0; ks < 2; ks++)
#pragma unroll
      for (int ni = 0; ni < 4; ni++)
        V[ks][ni] = *(const bf16x8*)(vbase + (size_t)(ni * 16 + r16) * S2c + k0 +
                                     ks * 32 + quad * 8);
    if (j + 1 < n) loadK(j + 1, Kn);

    // QK with K prefetched one unit ago (already resident)
    f32x4 sacc[4] = {};
#pragma unroll
    for (int ks = 0; ks < 2; ks++)
#pragma unroll
      for (int ni = 0; ni < 4; ni++) sacc[ni] = mfma16(aq[ks], K[ks][ni], sacc[ni]);

    const int mode = (half == 0) ? ((j == n - 1) ? 1 : 0) : ((j == 0) ? 2 : 0);
#pragma unroll
    for (int r = 0; r < 4; r++) {
      const int qrow = qw + quad * 4 + r;
#pragma unroll
      for (int ni = 0; ni < 4; ni++) {
        float s = sacc[ni][r];
        if (mode == 1) { const int key = k0 + ni * 16 + r16; if (key > qrow) s = -128.0f; }
        else if (mode == 2) { const int key = k0 - Sc + ni * 16 + r16; if (key < qrow) s = -128.0f; }
        const float pe = __builtin_amdgcn_exp2f(s);
        lsum[r] += pe;
        ps[(quad * 4 + r) * 68 + ni * 16 + r16] = f2b_fast(pe);
      }
    }

#pragma unroll
    for (int ks = 0; ks < 2; ks++) {
      const bf16x8 ap = *(const bf16x8*)(&ps[r16 * 68 + ks * 32 + quad * 8]);
#pragma unroll
      for (int ni = 0; ni < 4; ni++) o_acc[ni] = mfma16(ap, V[ks][ni], o_acc[ni]);
    }
  };

  loadK(0, KA);
  int j = 0;
  for (;;) {
    unit(j, KA, KB);
    if (++j >= n) break;
    unit(j, KB, KA);
    if (++j >= n) break;
  }

#pragma unroll
  for (int r = 0; r < 4; r++) {
    float l = lsum[r];
    l += __shfl_xor(l, 1);
    l += __shfl_xor(l, 2);
    l += __shfl_xor(l, 4);
    l += __shfl_xor(l, 8);
    lsum[r] = l;
  }

  const size_t rowbase = (((size_t)half * Bc + b) * Hc + head) * Sc + qw;
  float* ob = o_part + rowbase * HDc;
#pragma unroll
  for (int r = 0; r < 4; r++) {
    const int rl = quad * 4 + r;
#pragma unroll
    for (int ni = 0; ni < 4; ni++) ob[(size_t)rl * HDc + ni * 16 + r16] = o_acc[ni][r];
    if (r16 == 0) l_part[rowbase + rl] = lsum[r];
  }
}

// ---------------- combine halves + normalize -> bf16 [b,q,h,d] ----------------
__global__ __launch_bounds__(256) void attn_norm_kernel(const float* __restrict__ o_part,
                                                        const float* __restrict__ l_part,
                                                        u16* __restrict__ ob) {
  constexpr size_t HS = (size_t)Bc * Hc * Sc * HDc;
  constexpr size_t HL = (size_t)Bc * Hc * Sc;
  const int flat = blockIdx.x * 256 + threadIdx.x;
  const int row = flat >> 4, d0 = (flat & 15) * 4;
  const int q = row & (Sc - 1), h = (row >> 10) & 15, b = row >> 14;
  const float4 o0 = *(const float4*)(o_part + (size_t)row * HDc + d0);
  const float4 o1 = *(const float4*)(o_part + HS + (size_t)row * HDc + d0);
  const float rl = 1.0f / (l_part[row] + l_part[HL + row]);
  ushort4 o;
  o.x = f2b((o0.x + o1.x) * rl);
  o.y = f2b((o0.y + o1.y) * rl);
  o.z = f2b((o0.z + o1.z) * rl);
  o.w = f2b((o0.w + o1.w) * rl);
  *(ushort4*)(ob + ((size_t)((b * Sc + q) * Hc + h)) * HDc + d0) = o;
}

extern "C" void kernel_launch(void* const* d_in, const int* in_sizes, int n_in, void* d_out,
                              int out_size, void* d_ws, size_t ws_size, hipStream_t stream) {
  const float* fwd = (const float*)d_in[0];
  const float* bwd = (const float*)d_in[1];
  const float* pos = (const float*)d_in[2];
  const float* ln1g = (const float*)d_in[3];
  const float* ln1b = (const float*)d_in[4];
  const float* Wq = (const float*)d_in[5];
  const float* bq = (const float*)d_in[6];
  const float* Wk = (const float*)d_in[7];
  const float* bk = (const float*)d_in[8];
  const float* Wv = (const float*)d_in[9];
  const float* bv = (const float*)d_in[10];
  const float* Wo = (const float*)d_in[11];
  const float* bo = (const float*)d_in[12];
  const float* ln2g = (const float*)d_in[13];
  const float* ln2b = (const float*)d_in[14];
  const float* mlpg = (const float*)d_in[15];
  const float* mlpb = (const float*)d_in[16];
  const float* W1 = (const float*)d_in[17];
  const float* b1 = (const float*)d_in[18];
  const float* W2 = (const float*)d_in[19];
  const float* b2 = (const float*)d_in[20];

  char* p = (char*)d_ws;
  auto alloc = [&](size_t bytes) -> char* {
    char* r = p;
    p += (bytes + 255) & ~(size_t)255;
    return r;
  };
  float* comb = (float*)alloc((size_t)BSc * Cc * 4);
  float* xbuf = (float*)alloc((size_t)BSc * Cc * 4);
  u16* cx = (u16*)alloc((size_t)BSc * Cc * 2);
  u16* ae = (u16*)alloc((size_t)BS2c * Cc * 2);
  u16* qbuf = (u16*)alloc((size_t)BSc * Cc * 2);
  u16* kbuf = (u16*)alloc((size_t)BS2c * Cc * 2);
  u16* vTb = (u16*)alloc((size_t)BS2c * Cc * 2);
  u16* obuf = (u16*)alloc((size_t)BSc * Cc * 2);
  u16* hb = (u16*)alloc((size_t)BSc * Cc * 2);
  char* big = alloc((size_t)2 * BSc * Hc * HDc * 4 > (size_t)BSc * ECc * 2
                        ? (size_t)2 * BSc * Hc * HDc * 4
                        : (size_t)BSc * ECc * 2);
  float* o_part = (float*)big;
  u16* midb = (u16*)big;
  float* l_part = (float*)alloc((size_t)2 * Bc * Hc * Sc * 4);
  float* pbuf = (float*)alloc((size_t)4 * BSc * Cc * 4);  // 4 split-K slices of 2048x1024 f32
  u16* WqT = (u16*)alloc((size_t)Cc * Cc * 2);
  u16* WkvT = (u16*)alloc((size_t)2 * Cc * Cc * 2);
  u16* WoT = (u16*)alloc((size_t)Cc * Cc * 2);
  u16* W1T = (u16*)alloc((size_t)ECc * Cc * 2);
  u16* W2T = (u16*)alloc((size_t)Cc * ECc * 2);

  const dim3 tb(32, 8);
  transpose4_kernel<<<dim3(32, 32, 4), tb, 0, stream>>>(Wq, Wk, Wv, Wo, WqT, WkvT, WoT);
  transpose_kernel<<<dim3(128, 32), tb, 0, stream>>>(W1, W1T, Cc, ECc);
  transpose_kernel<<<dim3(32, 128), tb, 0, stream>>>(W2, W2T, ECc, Cc);

  prep_ln_kernel<<<BSc + BS2c, 256, 0, stream>>>(fwd, bwd, ln1g, ln1b, comb, cx, ae);

  // Q = cx @ WqT^T  (split-K=4 -> 512 blocks)
  gemm_kernel<EPI_PART, 4><<<dim3(Cc / 128, BSc / 128, 4), 256, 0, stream>>>(
      cx, WqT, nullptr, nullptr, nullptr, nullptr, nullptr, pbuf, BSc, Cc, Cc);
  reduce_kernel<EPI_Q, 4><<<(BSc * Cc / 4) / 256, 256, 0, stream>>>(
      pbuf, bq, pos, nullptr, qbuf, nullptr, BSc, Cc);

  // K,V fused (N=2048, 512 blocks)
  gemm_kernel<EPI_KV, 1><<<dim3(2 * Cc / 128, BS2c / 128, 1), 256, 0, stream>>>(
      ae, WkvT, bk, bv, pos, kbuf, vTb, nullptr, BS2c, 2 * Cc, Cc);

  attn_part_kernel<<<dim3(Bc * Hc, Sc / 64, 2), 256, 0, stream>>>(qbuf, kbuf, vTb, o_part,
                                                                  l_part);
  attn_norm_kernel<<<(BSc * Hc * HDc / 4) / 256, 256, 0, stream>>>(o_part, l_part, obuf);

  // x = comb + (o @ WoT^T + bo)  (split-K=4)
  gemm_kernel<EPI_PART, 4><<<dim3(Cc / 128, BSc / 128, 4), 256, 0, stream>>>(
      obuf, WoT, nullptr, nullptr, nullptr, nullptr, nullptr, pbuf, BSc, Cc, Cc);
  reduce_kernel<EPI_O, 4><<<(BSc * Cc / 4) / 256, 256, 0, stream>>>(
      pbuf, bo, nullptr, comb, nullptr, xbuf, BSc, Cc);

  ln2_kernel<<<BSc, 256, 0, stream>>>(xbuf, ln2g, ln2b, mlpg, mlpb, hb);

  // mid = gelu(h @ W1T^T + b1)  (512 blocks)
  gemm_kernel<EPI_GELU, 1><<<dim3(ECc / 128, BSc / 128, 1), 256, 0, stream>>>(
      hb, W1T, b1, nullptr, nullptr, midb, nullptr, nullptr, BSc, ECc, Cc);

  // out = x + (mid @ W2T^T + b2)  (split-K=4 over K=4096 -> 512 blocks)
  gemm_kernel<EPI_PART, 4><<<dim3(Cc / 128, BSc / 128, 4), 256, 0, stream>>>(
      midb, W2T, nullptr, nullptr, nullptr, nullptr, nullptr, pbuf, BSc, Cc, ECc);
  reduce_kernel<EPI_FINAL, 4><<<(BSc * Cc / 4) / 256, 256, 0, stream>>>(
      pbuf, b2, nullptr, xbuf, nullptr, (float*)d_out, BSc, Cc);
}

// Round 10
// 361.349 us; speedup vs baseline: 1.0944x; 1.0944x over previous
//
#include <hip/hip_runtime.h>
#include <hip/hip_bf16.h>
#include <cstdint>

#define DI __device__ __forceinline__

typedef unsigned short u16;
typedef __bf16 bf16x8 __attribute__((ext_vector_type(8)));
typedef float f32x4 __attribute__((ext_vector_type(4)));

constexpr int Bc  = 2;
constexpr int Sc  = 1024;
constexpr int Cc  = 1024;
constexpr int Hc  = 16;
constexpr int HDc = 64;
constexpr int S2c = 2048;
constexpr int ECc = 4096;
constexpr int BSc  = Bc * Sc;   // 2048
constexpr int BS2c = Bc * S2c;  // 4096

constexpr int EPI_KV = 0, EPI_Q = 1, EPI_O = 3, EPI_GELU = 4, EPI_FINAL = 5, EPI_PART = 6;

DI u16 f2b(float f) {
  __hip_bfloat16 h = __float2bfloat16(f);
  u16 u;
  __builtin_memcpy(&u, &h, 2);
  return u;
}

// fast bf16 pack (round-half-up); fine for p in [0,1]
DI u16 f2b_fast(float f) {
  uint32_t u;
  __builtin_memcpy(&u, &f, 4);
  return (u16)((u + 0x8000u) >> 16);
}

// CK-style direct global->LDS (16B per lane; LDS dest = wave-uniform base + lane*16)
DI void glds16(const void* g, void* l) {
  auto* lp = reinterpret_cast<__attribute__((address_space(3))) uint32_t*>(
      reinterpret_cast<uintptr_t>(l));
  __builtin_amdgcn_global_load_lds(
      reinterpret_cast<const __attribute__((address_space(1))) uint32_t*>(
          reinterpret_cast<uintptr_t>(g)),
      lp, 16, 0, 0);
}

DI f32x4 mfma16(bf16x8 a, bf16x8 b, f32x4 c) {
  return __builtin_amdgcn_mfma_f32_16x16x32_bf16(a, b, c, 0, 0, 0);
}

// ------------- fused transpose of the four CxC weights: WT[n][k] = W[k][n] -------------
__global__ __launch_bounds__(256) void transpose4_kernel(const float* __restrict__ Wq,
                                                         const float* __restrict__ Wk,
                                                         const float* __restrict__ Wv,
                                                         const float* __restrict__ Wo,
                                                         u16* __restrict__ WqT,
                                                         u16* __restrict__ WkvT,
                                                         u16* __restrict__ WoT) {
  __shared__ float tile[32][33];
  const int z = blockIdx.z;
  const float* W = (z == 0) ? Wq : (z == 1) ? Wk : (z == 2) ? Wv : Wo;
  u16* WT = (z == 0) ? WqT : (z == 1) ? WkvT : (z == 2) ? (WkvT + (size_t)Cc * Cc) : WoT;
  const int bx = blockIdx.x, by = blockIdx.y;
  const int tx = threadIdx.x, ty = threadIdx.y;
  const int c = bx * 32 + tx;
#pragma unroll
  for (int i = ty; i < 32; i += 8) tile[i][tx] = W[(size_t)(by * 32 + i) * Cc + c];
  __syncthreads();
#pragma unroll
  for (int i = ty; i < 32; i += 8)
    WT[(size_t)(bx * 32 + i) * Cc + by * 32 + tx] = f2b(tile[tx][i]);
}

// ---------------- transpose + fp32->bf16 convert: WT[n][k] = W[k][n] ----------------
__global__ __launch_bounds__(256) void transpose_kernel(const float* __restrict__ W,
                                                        u16* __restrict__ WT, int R, int Cn) {
  __shared__ float tile[32][33];
  const int bx = blockIdx.x, by = blockIdx.y;
  const int tx = threadIdx.x, ty = threadIdx.y;
  const int c = bx * 32 + tx;
#pragma unroll
  for (int i = ty; i < 32; i += 8) tile[i][tx] = W[(size_t)(by * 32 + i) * Cn + c];
  __syncthreads();
#pragma unroll
  for (int i = ty; i < 32; i += 8)
    WT[(size_t)(bx * 32 + i) * R + by * 32 + tx] = f2b(tile[tx][i]);
}

// ---------------- prep: comb + LN(comb)->cx ; LN(all_embed)->ae ----------------
__global__ __launch_bounds__(256) void prep_ln_kernel(
    const float* __restrict__ fwd, const float* __restrict__ bwd, const float* __restrict__ g,
    const float* __restrict__ be, float* __restrict__ comb, u16* __restrict__ cx,
    u16* __restrict__ ae) {
  __shared__ float red[2][4];
  const int row = blockIdx.x, tid = threadIdx.x;
  const int c = tid * 4;
  float4 x;
  u16* dst;
  if (row < BSc) {
    const int b = row >> 10, s = row & (Sc - 1);
    const float4 f = *(const float4*)(fwd + ((size_t)(b * (Sc + 1) + s)) * Cc + c);
    const float4 r = *(const float4*)(bwd + ((size_t)(b * (Sc + 1) + s + 1)) * Cc + c);
    const float k = 0.70710678118654752f;
    x.x = (f.x + r.x) * k; x.y = (f.y + r.y) * k;
    x.z = (f.z + r.z) * k; x.w = (f.w + r.w) * k;
    *(float4*)(comb + (size_t)row * Cc + c) = x;
    dst = cx + (size_t)row * Cc;
  } else {
    const int idx = row - BSc;
    const int b = idx >> 11, t = idx & (S2c - 1);
    const float* src = (t < Sc) ? (fwd + ((size_t)(b * (Sc + 1) + t)) * Cc)
                                : (bwd + ((size_t)(b * (Sc + 1) + (t - Sc) + 1)) * Cc);
    x = *(const float4*)(src + c);
    dst = ae + (size_t)idx * Cc;
  }
  float s1 = x.x + x.y + x.z + x.w;
  float s2 = x.x * x.x + x.y * x.y + x.z * x.z + x.w * x.w;
  for (int off = 32; off; off >>= 1) { s1 += __shfl_down(s1, off); s2 += __shfl_down(s2, off); }
  if ((tid & 63) == 0) { red[0][tid >> 6] = s1; red[1][tid >> 6] = s2; }
  __syncthreads();
  s1 = red[0][0] + red[0][1] + red[0][2] + red[0][3];
  s2 = red[1][0] + red[1][1] + red[1][2] + red[1][3];
  const float mean = s1 * (1.0f / Cc);
  const float rstd = rsqrtf(s2 * (1.0f / Cc) - mean * mean + 1e-5f);
  const float4 gv = *(const float4*)(g + c);
  const float4 bv = *(const float4*)(be + c);
  ushort4 o;
  o.x = f2b((x.x - mean) * rstd * gv.x + bv.x);
  o.y = f2b((x.y - mean) * rstd * gv.y + bv.y);
  o.z = f2b((x.z - mean) * rstd * gv.z + bv.z);
  o.w = f2b((x.w - mean) * rstd * gv.w + bv.w);
  *(ushort4*)(dst + c) = o;
}

// ---------------- double LN: h = LN(LN(x,g2,b2),gm,bm) ----------------
__global__ __launch_bounds__(256) void ln2_kernel(const float* __restrict__ x,
                                                  const float* __restrict__ g2,
                                                  const float* __restrict__ b2,
                                                  const float* __restrict__ gm,
                                                  const float* __restrict__ bm,
                                                  u16* __restrict__ h) {
  __shared__ float red[2][4];
  const int row = blockIdx.x, tid = threadIdx.x;
  const int c = tid * 4;
  const float4 v = *(const float4*)(x + (size_t)row * Cc + c);
  float s1 = v.x + v.y + v.z + v.w;
  float s2 = v.x * v.x + v.y * v.y + v.z * v.z + v.w * v.w;
  for (int off = 32; off; off >>= 1) { s1 += __shfl_down(s1, off); s2 += __shfl_down(s2, off); }
  if ((tid & 63) == 0) { red[0][tid >> 6] = s1; red[1][tid >> 6] = s2; }
  __syncthreads();
  s1 = red[0][0] + red[0][1] + red[0][2] + red[0][3];
  s2 = red[1][0] + red[1][1] + red[1][2] + red[1][3];
  float mean = s1 * (1.0f / Cc);
  float rstd = rsqrtf(s2 * (1.0f / Cc) - mean * mean + 1e-5f);
  const float4 ga = *(const float4*)(g2 + c);
  const float4 ba = *(const float4*)(b2 + c);
  const float t0 = (v.x - mean) * rstd * ga.x + ba.x;
  const float t1 = (v.y - mean) * rstd * ga.y + ba.y;
  const float t2 = (v.z - mean) * rstd * ga.z + ba.z;
  const float t3 = (v.w - mean) * rstd * ga.w + ba.w;
  s1 = t0 + t1 + t2 + t3;
  s2 = t0 * t0 + t1 * t1 + t2 * t2 + t3 * t3;
  for (int off = 32; off; off >>= 1) { s1 += __shfl_down(s1, off); s2 += __shfl_down(s2, off); }
  __syncthreads();
  if ((tid & 63) == 0) { red[0][tid >> 6] = s1; red[1][tid >> 6] = s2; }
  __syncthreads();
  s1 = red[0][0] + red[0][1] + red[0][2] + red[0][3];
  s2 = red[1][0] + red[1][1] + red[1][2] + red[1][3];
  mean = s1 * (1.0f / Cc);
  rstd = rsqrtf(s2 * (1.0f / Cc) - mean * mean + 1e-5f);
  const float4 gb = *(const float4*)(gm + c);
  const float4 bb = *(const float4*)(bm + c);
  ushort4 o;
  o.x = f2b((t0 - mean) * rstd * gb.x + bb.x);
  o.y = f2b((t1 - mean) * rstd * gb.y + bb.y);
  o.z = f2b((t2 - mean) * rstd * gb.z + bb.z);
  o.w = f2b((t3 - mean) * rstd * gb.w + bb.w);
  *(ushort4*)(h + (size_t)row * Cc + c) = o;
}

// ---------------- GEMM: Y = A(MxK) @ BT(NxK)^T, fused epilogues ----------------
// 128x128 tile, 4 waves (64x64 each), BK=32, glds16 staging, 2-barrier K-loop
// (the R5-benched structure — best measured). Optional split-K via gridDim.z:
// slice z covers K/SK; EPI_PART writes raw f32 partials to pbuf[z].
template <int EPI, int SK>
__global__ __launch_bounds__(256) void gemm_kernel(
    const u16* __restrict__ A, const u16* __restrict__ BT, const float* __restrict__ bias,
    const float* __restrict__ bias2, const float* __restrict__ pos,
    u16* __restrict__ outb, u16* __restrict__ out2, float* __restrict__ pbuf,
    int M, int N, int K) {
  __shared__ u16 Asm[128 * 32];
  __shared__ u16 Bsm[128 * 32];
  const int tid = threadIdx.x;
  const int w = tid >> 6, lane = tid & 63, quad = lane >> 4, r16 = lane & 15;
  const int bm = blockIdx.y * 128, bn = blockIdx.x * 128;
  const int wm = (w & 1) * 64, wn = (w >> 1) * 64;
  const int Ks = K / SK, kb0 = blockIdx.z * Ks;

  const int srow = lane >> 2, scol = (lane & 3) * 8;
  const u16* aP = A + (size_t)(bm + w * 32 + srow) * K + kb0 + scol;
  const u16* bP = BT + (size_t)(bn + w * 32 + srow) * K + kb0 + scol;
  u16* aL0 = &Asm[(w * 32) * 32];
  u16* aL1 = &Asm[(w * 32 + 16) * 32];
  u16* bL0 = &Bsm[(w * 32) * 32];
  u16* bL1 = &Bsm[(w * 32 + 16) * 32];
  const size_t rstep = (size_t)16 * K;

  f32x4 acc[4][4] = {};

  for (int k0 = 0; k0 < Ks; k0 += 32) {
    glds16(aP, aL0);
    glds16(aP + rstep, aL1);
    glds16(bP, bL0);
    glds16(bP + rstep, bL1);
    aP += 32;
    bP += 32;
    __syncthreads();
    bf16x8 af[4], bfr[4];
#pragma unroll
    for (int i = 0; i < 4; i++) {
      af[i] = *reinterpret_cast<const bf16x8*>(&Asm[(wm + i * 16 + r16) * 32 + quad * 8]);
      bfr[i] = *reinterpret_cast<const bf16x8*>(&Bsm[(wn + i * 16 + r16) * 32 + quad * 8]);
    }
#pragma unroll
    for (int mi = 0; mi < 4; mi++)
#pragma unroll
      for (int ni = 0; ni < 4; ni++) acc[mi][ni] = mfma16(af[mi], bfr[ni], acc[mi][ni]);
    __syncthreads();
  }

#pragma unroll
  for (int mi = 0; mi < 4; mi++) {
#pragma unroll
    for (int ni = 0; ni < 4; ni++) {
      const int col = bn + wn + ni * 16 + r16;
      const int row0 = bm + wm + mi * 16 + quad * 4;
      if constexpr (EPI == EPI_PART) {
        float* pb = pbuf + (size_t)blockIdx.z * M * N;
#pragma unroll
        for (int r = 0; r < 4; r++) pb[(size_t)(row0 + r) * N + col] = acc[mi][ni][r];
      } else if constexpr (EPI == EPI_KV) {
        if (col < Cc) {
#pragma unroll
          for (int r = 0; r < 4; r++) {
            const int row = row0 + r;
            const int key = row & (S2c - 1);
            const float y =
                acc[mi][ni][r] + bias[col] + pos[(key & (Sc - 1)) * HDc + (col & 63)];
            outb[(size_t)row * Cc + col] = f2b(y);
          }
        } else {
          const int c2 = col - Cc;
          const int h = c2 >> 6, d = c2 & 63;
          const int b = row0 >> 11, key0 = row0 & (S2c - 1);
          const float bb = bias2[c2];
          ushort4 pk;
          pk.x = f2b(acc[mi][ni][0] + bb);
          pk.y = f2b(acc[mi][ni][1] + bb);
          pk.z = f2b(acc[mi][ni][2] + bb);
          pk.w = f2b(acc[mi][ni][3] + bb);
          *(ushort4*)&out2[(((size_t)(b * Hc + h) * HDc + d) << 11) + key0] = pk;
        }
      } else {  // EPI_GELU
#pragma unroll
        for (int r = 0; r < 4; r++) {
          const float y = acc[mi][ni][r] + bias[col];
          outb[(size_t)(row0 + r) * N + col] =
              f2b(0.5f * y * (1.0f + erff(y * 0.70710678118654752f)));
        }
      }
    }
  }
}

// ---------------- split-K reduce + epilogue (SK slices of MxN f32) ----------------
// EPI_Q: out = bf16((sum + bias + pos) * scale) ; EPI_O/EPI_FINAL: out = f32(sum + bias + add)
template <int EPI, int SK>
__global__ __launch_bounds__(256) void reduce_kernel(const float* __restrict__ pbuf,
                                                     const float* __restrict__ bias,
                                                     const float* __restrict__ pos,
                                                     const float* __restrict__ addsrc,
                                                     u16* __restrict__ outb,
                                                     float* __restrict__ outf, int M, int N) {
  const size_t flat = ((size_t)blockIdx.x * 256 + threadIdx.x) * 4;
  const int row = (int)(flat / N), col = (int)(flat % N);
  const size_t MN = (size_t)M * N;
  float4 s = *(const float4*)(pbuf + flat);
#pragma unroll
  for (int z = 1; z < SK; z++) {
    const float4 v = *(const float4*)(pbuf + z * MN + flat);
    s.x += v.x; s.y += v.y; s.z += v.z; s.w += v.w;
  }
  const float4 bv = *(const float4*)(bias + col);
  s.x += bv.x; s.y += bv.y; s.z += bv.z; s.w += bv.w;
  if constexpr (EPI == EPI_Q) {
    const int sq = row & (Sc - 1), d = col & 63;
    const float4 pv = *(const float4*)(pos + sq * HDc + d);
    constexpr float sc = 0.180336880111120426f;  // (1/8)*log2(e)
    ushort4 o;
    o.x = f2b((s.x + pv.x) * sc);
    o.y = f2b((s.y + pv.y) * sc);
    o.z = f2b((s.z + pv.z) * sc);
    o.w = f2b((s.w + pv.w) * sc);
    *(ushort4*)(outb + flat) = o;
  } else {
    const float4 av = *(const float4*)(addsrc + flat);
    float4 o;
    o.x = s.x + av.x; o.y = s.y + av.y; o.z = s.z + av.z; o.w = s.w + av.w;
    *(float4*)(outf + flat) = o;
  }
}

// ---------------- attention partials: grid (bh, qt, half) ----------------
// K/V tiles staged ONCE per block via cooperative glds16 into LDS (shared by all 4
// waves — R8/R9 loaded them 4x redundantly through VGPRs and the allocator
// serialized the loads). 2-barrier unit loop, GEMM-style. Sub-tiles use 64-B rows
// so fragment ds_read_b128 banks = (r16&1)*16+quad*4 -> 2-way (free).
// qb: [b,q,h,d] bf16 (pre-scaled by (1/8)*log2e); kb: [b,key(2S),h,d]; vT: [b,h,d,key(2S)]
__global__ __launch_bounds__(256) void attn_part_kernel(const u16* __restrict__ qb,
                                                        const u16* __restrict__ kb,
                                                        const u16* __restrict__ vT,
                                                        float* __restrict__ o_part,
                                                        float* __restrict__ l_part) {
  const int bh = blockIdx.x;
  const int qt = blockIdx.y;
  const int half = blockIdx.z;
  const int b = bh >> 4, head = bh & 15;
  const int tid = threadIdx.x;
  const int w = tid >> 6, lane = tid & 63, quad = lane >> 4, r16 = lane & 15;

  __shared__ u16 Kt[2][64 * 32];  // [ks][key][32 d]   rows 64 B
  __shared__ u16 Vt[2][64 * 32];  // [ks][d][32 keys]  rows 64 B
  __shared__ u16 Ps[4][16 * 68];  // per-wave P round-trip (stride 68: conflict-free)
  u16* ps = Ps[w];

  const int q0 = qt * 64;
  const int qw = q0 + w * 16;  // this wave's 16 queries

  bf16x8 aq[2];
  {
    const u16* qp = qb + ((size_t)((b * Sc + qw + r16) * Hc + head)) * HDc + quad * 8;
    aq[0] = *(const bf16x8*)qp;
    aq[1] = *(const bf16x8*)(qp + 32);
  }

  const size_t krow = (size_t)Hc * HDc;
  const u16* kbase = kb + ((size_t)b * S2c * Hc + head) * HDc;
  const u16* vbase = vT + ((size_t)(b * Hc + head)) * HDc * S2c;

  // cooperative staging map: wave w covers rows w*16 + lane/4, 16 B at (lane&3)*8
  const int srow = w * 16 + (lane >> 2);
  const int scol = (lane & 3) * 8;
  u16* kD0 = &Kt[0][w * 16 * 32];
  u16* kD1 = &Kt[1][w * 16 * 32];
  u16* vD0 = &Vt[0][w * 16 * 32];
  u16* vD1 = &Vt[1][w * 16 * 32];
  const u16* kS = kbase + (size_t)srow * krow + scol;   // + key0*krow (+32 for ks=1)
  const u16* vS = vbase + (size_t)srow * S2c + scol;    // + key0     (+32 for ks=1)

  f32x4 o_acc[4] = {};
  float lsum[4] = {};

  const int n = (half == 0) ? (qt + 1) : (16 - qt);
  const int kb0 = (half == 0) ? 0 : Sc + qt * 64;  // unit j covers keys kb0 + j*64 ..

  for (int j = 0; j < n; j++) {
    const int k0 = kb0 + j * 64;
    glds16(kS + (size_t)k0 * krow, kD0);
    glds16(kS + (size_t)k0 * krow + 32, kD1);
    glds16(vS + k0, vD0);
    glds16(vS + k0 + 32, vD1);
    __syncthreads();

    // QK^T from LDS
    f32x4 sacc[4] = {};
#pragma unroll
    for (int ks = 0; ks < 2; ks++)
#pragma unroll
      for (int ni = 0; ni < 4; ni++) {
        const bf16x8 bk = *(const bf16x8*)&Kt[ks][(ni * 16 + r16) * 32 + quad * 8];
        sacc[ni] = mfma16(aq[ks], bk, sacc[ni]);
      }

    const int mode = (half == 0) ? ((j == n - 1) ? 1 : 0) : ((j == 0) ? 2 : 0);
#pragma unroll
    for (int r = 0; r < 4; r++) {
      const int qrow = qw + quad * 4 + r;
#pragma unroll
      for (int ni = 0; ni < 4; ni++) {
        float s = sacc[ni][r];
        if (mode == 1) { const int key = k0 + ni * 16 + r16; if (key > qrow) s = -128.0f; }
        else if (mode == 2) { const int key = k0 - Sc + ni * 16 + r16; if (key < qrow) s = -128.0f; }
        const float pe = __builtin_amdgcn_exp2f(s);
        lsum[r] += pe;
        ps[(quad * 4 + r) * 68 + ni * 16 + r16] = f2b_fast(pe);
      }
    }

    // PV from LDS
#pragma unroll
    for (int ks = 0; ks < 2; ks++) {
      const bf16x8 ap = *(const bf16x8*)(&ps[r16 * 68 + ks * 32 + quad * 8]);
#pragma unroll
      for (int ni = 0; ni < 4; ni++) {
        const bf16x8 bv_ = *(const bf16x8*)&Vt[ks][(ni * 16 + r16) * 32 + quad * 8];
        o_acc[ni] = mfma16(ap, bv_, o_acc[ni]);
      }
    }
    __syncthreads();
  }

#pragma unroll
  for (int r = 0; r < 4; r++) {
    float l = lsum[r];
    l += __shfl_xor(l, 1);
    l += __shfl_xor(l, 2);
    l += __shfl_xor(l, 4);
    l += __shfl_xor(l, 8);
    lsum[r] = l;
  }

  const size_t rowbase = (((size_t)half * Bc + b) * Hc + head) * Sc + qw;
  float* ob = o_part + rowbase * HDc;
#pragma unroll
  for (int r = 0; r < 4; r++) {
    const int rl = quad * 4 + r;
#pragma unroll
    for (int ni = 0; ni < 4; ni++) ob[(size_t)rl * HDc + ni * 16 + r16] = o_acc[ni][r];
    if (r16 == 0) l_part[rowbase + rl] = lsum[r];
  }
}

// ---------------- combine halves + normalize -> bf16 [b,q,h,d] ----------------
__global__ __launch_bounds__(256) void attn_norm_kernel(const float* __restrict__ o_part,
                                                        const float* __restrict__ l_part,
                                                        u16* __restrict__ ob) {
  constexpr size_t HS = (size_t)Bc * Hc * Sc * HDc;
  constexpr size_t HL = (size_t)Bc * Hc * Sc;
  const int flat = blockIdx.x * 256 + threadIdx.x;
  const int row = flat >> 4, d0 = (flat & 15) * 4;
  const int q = row & (Sc - 1), h = (row >> 10) & 15, b = row >> 14;
  const float4 o0 = *(const float4*)(o_part + (size_t)row * HDc + d0);
  const float4 o1 = *(const float4*)(o_part + HS + (size_t)row * HDc + d0);
  const float rl = 1.0f / (l_part[row] + l_part[HL + row]);
  ushort4 o;
  o.x = f2b((o0.x + o1.x) * rl);
  o.y = f2b((o0.y + o1.y) * rl);
  o.z = f2b((o0.z + o1.z) * rl);
  o.w = f2b((o0.w + o1.w) * rl);
  *(ushort4*)(ob + ((size_t)((b * Sc + q) * Hc + h)) * HDc + d0) = o;
}

extern "C" void kernel_launch(void* const* d_in, const int* in_sizes, int n_in, void* d_out,
                              int out_size, void* d_ws, size_t ws_size, hipStream_t stream) {
  const float* fwd = (const float*)d_in[0];
  const float* bwd = (const float*)d_in[1];
  const float* pos = (const float*)d_in[2];
  const float* ln1g = (const float*)d_in[3];
  const float* ln1b = (const float*)d_in[4];
  const float* Wq = (const float*)d_in[5];
  const float* bq = (const float*)d_in[6];
  const float* Wk = (const float*)d_in[7];
  const float* bk = (const float*)d_in[8];
  const float* Wv = (const float*)d_in[9];
  const float* bv = (const float*)d_in[10];
  const float* Wo = (const float*)d_in[11];
  const float* bo = (const float*)d_in[12];
  const float* ln2g = (const float*)d_in[13];
  const float* ln2b = (const float*)d_in[14];
  const float* mlpg = (const float*)d_in[15];
  const float* mlpb = (const float*)d_in[16];
  const float* W1 = (const float*)d_in[17];
  const float* b1 = (const float*)d_in[18];
  const float* W2 = (const float*)d_in[19];
  const float* b2 = (const float*)d_in[20];

  char* p = (char*)d_ws;
  auto alloc = [&](size_t bytes) -> char* {
    char* r = p;
    p += (bytes + 255) & ~(size_t)255;
    return r;
  };
  float* comb = (float*)alloc((size_t)BSc * Cc * 4);
  float* xbuf = (float*)alloc((size_t)BSc * Cc * 4);
  u16* cx = (u16*)alloc((size_t)BSc * Cc * 2);
  u16* ae = (u16*)alloc((size_t)BS2c * Cc * 2);
  u16* qbuf = (u16*)alloc((size_t)BSc * Cc * 2);
  u16* kbuf = (u16*)alloc((size_t)BS2c * Cc * 2);
  u16* vTb = (u16*)alloc((size_t)BS2c * Cc * 2);
  u16* obuf = (u16*)alloc((size_t)BSc * Cc * 2);
  u16* hb = (u16*)alloc((size_t)BSc * Cc * 2);
  char* big = alloc((size_t)2 * BSc * Hc * HDc * 4 > (size_t)BSc * ECc * 2
                        ? (size_t)2 * BSc * Hc * HDc * 4
                        : (size_t)BSc * ECc * 2);
  float* o_part = (float*)big;
  u16* midb = (u16*)big;
  float* l_part = (float*)alloc((size_t)2 * Bc * Hc * Sc * 4);
  float* pbuf = (float*)alloc((size_t)4 * BSc * Cc * 4);  // 4 split-K slices of 2048x1024 f32
  u16* WqT = (u16*)alloc((size_t)Cc * Cc * 2);
  u16* WkvT = (u16*)alloc((size_t)2 * Cc * Cc * 2);
  u16* WoT = (u16*)alloc((size_t)Cc * Cc * 2);
  u16* W1T = (u16*)alloc((size_t)ECc * Cc * 2);
  u16* W2T = (u16*)alloc((size_t)Cc * ECc * 2);

  const dim3 tb(32, 8);
  transpose4_kernel<<<dim3(32, 32, 4), tb, 0, stream>>>(Wq, Wk, Wv, Wo, WqT, WkvT, WoT);
  transpose_kernel<<<dim3(128, 32), tb, 0, stream>>>(W1, W1T, Cc, ECc);
  transpose_kernel<<<dim3(32, 128), tb, 0, stream>>>(W2, W2T, ECc, Cc);

  prep_ln_kernel<<<BSc + BS2c, 256, 0, stream>>>(fwd, bwd, ln1g, ln1b, comb, cx, ae);

  // Q = cx @ WqT^T  (split-K=4 -> 512 blocks)
  gemm_kernel<EPI_PART, 4><<<dim3(Cc / 128, BSc / 128, 4), 256, 0, stream>>>(
      cx, WqT, nullptr, nullptr, nullptr, nullptr, nullptr, pbuf, BSc, Cc, Cc);
  reduce_kernel<EPI_Q, 4><<<(BSc * Cc / 4) / 256, 256, 0, stream>>>(
      pbuf, bq, pos, nullptr, qbuf, nullptr, BSc, Cc);

  // K,V fused (N=2048, 512 blocks)
  gemm_kernel<EPI_KV, 1><<<dim3(2 * Cc / 128, BS2c / 128, 1), 256, 0, stream>>>(
      ae, WkvT, bk, bv, pos, kbuf, vTb, nullptr, BS2c, 2 * Cc, Cc);

  attn_part_kernel<<<dim3(Bc * Hc, Sc / 64, 2), 256, 0, stream>>>(qbuf, kbuf, vTb, o_part,
                                                                  l_part);
  attn_norm_kernel<<<(BSc * Hc * HDc / 4) / 256, 256, 0, stream>>>(o_part, l_part, obuf);

  // x = comb + (o @ WoT^T + bo)  (split-K=4)
  gemm_kernel<EPI_PART, 4><<<dim3(Cc / 128, BSc / 128, 4), 256, 0, stream>>>(
      obuf, WoT, nullptr, nullptr, nullptr, nullptr, nullptr, pbuf, BSc, Cc, Cc);
  reduce_kernel<EPI_O, 4><<<(BSc * Cc / 4) / 256, 256, 0, stream>>>(
      pbuf, bo, nullptr, comb, nullptr, xbuf, BSc, Cc);

  ln2_kernel<<<BSc, 256, 0, stream>>>(xbuf, ln2g, ln2b, mlpg, mlpb, hb);

  // mid = gelu(h @ W1T^T + b1)  (512 blocks)
  gemm_kernel<EPI_GELU, 1><<<dim3(ECc / 128, BSc / 128, 1), 256, 0, stream>>>(
      hb, W1T, b1, nullptr, nullptr, midb, nullptr, nullptr, BSc, ECc, Cc);

  // out = x + (mid @ W2T^T + b2)  (split-K=4 over K=4096 -> 512 blocks)
  gemm_kernel<EPI_PART, 4><<<dim3(Cc / 128, BSc / 128, 4), 256, 0, stream>>>(
      midb, W2T, nullptr, nullptr, nullptr, nullptr, nullptr, pbuf, BSc, Cc, ECc);
  reduce_kernel<EPI_FINAL, 4><<<(BSc * Cc / 4) / 256, 256, 0, stream>>>(
      pbuf, b2, nullptr, xbuf, nullptr, (float*)d_out, BSc, Cc);
}